// Round 12
// baseline (116.664 us; speedup 1.0000x reference)
//
#include <hip/hip_runtime.h>
#include <math.h>

#define FDIM  100
#define ODIM  180
#define HTOT  512
#define WTOT  512
#define TW    32               // tile width (pixels)
#define TH    16               // tile height (pixels)
#define LDSW  49
#define NSLICE 8
#define SLICE_SZ 2250          // 18000/8 -> per-XCD-resident 2.6 MB slice
#define NTILE 512              // (512/32) * (512/16)
#define NBLK  (NTILE * NSLICE) // 4096 blocks
#define TEMPERATURE 20.0f
#define THRESHOLD   55.0f

typedef float f32x2 __attribute__((ext_vector_type(2)));
typedef float f32x4 __attribute__((ext_vector_type(4)));

// ws layout (bytes): [0, 32768) : float2 partial[4096] — all written every call
__global__ __launch_bounds__(128, 8) void filter_sliced(
    const float* __restrict__ x,
    const int*   __restrict__ freq,
    const int*   __restrict__ orient,
    const float* __restrict__ fb,
    float*       __restrict__ y,
    float2*      __restrict__ partial)
{
    __shared__ float tile[2 * TH][LDSW];       // 32 x 49 floats = 6272 B
    __shared__ int   sel[TW * TH];             // packed (idx<<9)|p, 2048 B
    __shared__ unsigned int nsel;

    const int gid   = blockIdx.x;
    const int slice = gid & (NSLICE - 1);
    const int t     = gid >> 3;                // tile id 0..511
    const int bx    = t & 15, by = t >> 4;     // 16 across, 32 down
    const int tid   = threadIdx.x;             // 0..127
    const int lane  = tid & 63;

    if (tid == 0) nsel = 0;
    __syncthreads();

    // pass 1: per-pixel filter index + wave-aggregated compaction
    const int lo = slice * SLICE_SZ;
    #pragma unroll
    for (int k = 0; k < 4; ++k) {
        const int p  = tid + k * 128;
        const int pr = p >> 5, pc = p & 31;
        const int pid = (by * TH + pr) * WTOT + bx * TW + pc;
        int f0 = freq[pid] - 1;
        int o0 = orient[pid] - 1;
        f0 = f0 < 0 ? 0 : (f0 > FDIM - 1 ? FDIM - 1 : f0);
        o0 = o0 < 0 ? 0 : (o0 > ODIM - 1 ? ODIM - 1 : o0);
        const int idx = f0 * ODIM + o0;
        const bool want = (idx >= lo && idx < lo + SLICE_SZ);
        const unsigned long long mask = __ballot(want);
        unsigned int base = 0;
        if (lane == 0) base = atomicAdd(&nsel, (unsigned int)__popcll(mask));
        base = __shfl(base, 0, 64);
        if (want) {
            const int pos = __popcll(mask & ((1ULL << lane) - 1ULL));
            sel[base + pos] = (idx << 9) | p;
        }
    }

    // stage 32x48 input region (zero-padded at image borders)
    const int h0 = by * TH - 8;
    const int w0 = bx * TW - 8;
    for (int i = tid; i < 32 * 48; i += 128) {
        const int r = i / 48, c = i - r * 48;
        const int gh = h0 + r, gw = w0 + c;
        float v = 0.f;
        if (gh >= 0 && gh < HTOT && gw >= 0 && gw < WTOT)
            v = x[gh * WTOT + gw];
        tile[r][c] = v;
    }
    __syncthreads();

    const unsigned int m = nsel;
    const int l  = tid & 15;                   // lane within quarter-wave
    const int qw = tid >> 4;                   // quarter-wave id 0..7

    // odd-j rotation: odd qws run the j-schedule 9 positions later -> their
    // LDS bank windows sit 16 banks from even qws' (16*dj mod 32, dj=9 odd),
    // halving cross-qw conflicts. Bijective reorder; dot-product unchanged.
    const int rot = (qw & 1) * 9;

    int offs[18];
    #pragma unroll
    for (int j = 0; j < 18; ++j) {
        int jr = j + rot; if (jr >= 18) jr -= 18;
        const int e = jr * 16 + l;
        offs[j] = (e / 17) * LDSW + (e % 17);
    }

    float mn = 3.4e38f, mx = -3.4e38f;

    for (unsigned int s = qw; s < m; s += 8) {
        const int packed = sel[s];
        const int tp  = packed & 511;
        const int ppy = tp >> 5, ppx = tp & 31;
        const float* __restrict__ kf = fb + (size_t)(packed >> 9) * 289;

        float kv[18];
        #pragma unroll
        for (int j = 0; j < 18; ++j) {
            int jr = j + rot; if (jr >= 18) jr -= 18;
            kv[j] = kf[jr * 16 + l];
        }
        const float kt = kf[288];

        const float* __restrict__ base = &tile[ppy][ppx];
        float a0 = 0.f, a1 = 0.f, a2 = 0.f, a3 = 0.f;
        #pragma unroll
        for (int j = 0; j < 16; j += 4) {
            a0 = fmaf(kv[j    ], base[offs[j    ]], a0);
            a1 = fmaf(kv[j + 1], base[offs[j + 1]], a1);
            a2 = fmaf(kv[j + 2], base[offs[j + 2]], a2);
            a3 = fmaf(kv[j + 3], base[offs[j + 3]], a3);
        }
        a0 = fmaf(kv[16], base[offs[16]], a0);
        a1 = fmaf(kv[17], base[offs[17]], a1);
        float acc = (a0 + a1) + (a2 + a3);
        if (l == 0) acc = fmaf(kt, base[16 * LDSW + 16], acc);  // e = 288 tail

        // butterfly sum over the 16-lane group
        #pragma unroll
        for (int off = 8; off; off >>= 1)
            acc += __shfl_xor(acc, off, 64);

        if (l == 0)
            y[(by * TH + ppy) * WTOT + bx * TW + ppx] = acc;
        mn = fminf(mn, acc);
        mx = fmaxf(mx, acc);
    }

    // ---- block min/max reduce (2 waves), one plain store to a unique slot ----
    #pragma unroll
    for (int off = 32; off > 0; off >>= 1) {
        mn = fminf(mn, __shfl_down(mn, off, 64));
        mx = fmaxf(mx, __shfl_down(mx, off, 64));
    }
    __shared__ float smn[2], smx[2];
    const int wid = tid >> 6;
    if (lane == 0) { smn[wid] = mn; smx[wid] = mx; }
    __syncthreads();
    if (tid == 0) {
        const float bmn = fminf(smn[0], smn[1]);
        const float bmx = fmaxf(smx[0], smx[1]);
        partial[gid] = make_float2(bmn, bmx);
    }
}

// fused: re-reduce the 4096 partials (32 KB, L2-hit) + transform 2 px/thread
__global__ __launch_bounds__(256) void filter_final(
    float* __restrict__ y,
    const float2* __restrict__ partial)
{
    const int tid = threadIdx.x;
    float mn = 3.4e38f, mx = -3.4e38f;
    const f32x4* __restrict__ p4 = reinterpret_cast<const f32x4*>(partial);
    for (int i = tid; i < NBLK / 2; i += 256) {      // 8 iters, 2 pairs each
        const f32x4 p = p4[i];
        mn = fminf(mn, fminf(p.x, p.z));
        mx = fmaxf(mx, fmaxf(p.y, p.w));
    }
    #pragma unroll
    for (int off = 32; off > 0; off >>= 1) {
        mn = fminf(mn, __shfl_down(mn, off, 64));
        mx = fmaxf(mx, __shfl_down(mx, off, 64));
    }
    __shared__ float smn[4], smx[4];
    const int wid = tid >> 6, lane = tid & 63;
    if (lane == 0) { smn[wid] = mn; smx[wid] = mx; }
    __syncthreads();
    __shared__ float sfin[2];
    if (tid == 0) {
        float bmn = smn[0], bmx = smx[0];
        #pragma unroll
        for (int i = 1; i < 4; ++i) {
            bmn = fminf(bmn, smn[i]);
            bmx = fmaxf(bmx, smx[i]);
        }
        sfin[0] = bmn; sfin[1] = bmx;
    }
    __syncthreads();

    const float ymin = sfin[0];
    const float rng  = fmaxf(sfin[1] - ymin, 1e-8f);
    const float smin = 100.f / (1.f + expf( 11.f));   // 100*sigmoid(-11)
    const float smax = 100.f / (1.f + expf(-9.f));    // 100*sigmoid(+9)
    const float srng = fmaxf(smax - smin, 1e-8f);

    const int base = blockIdx.x * 512 + tid * 2;
    f32x2 v = *reinterpret_cast<const f32x2*>(&y[base]);
    #pragma unroll
    for (int i = 0; i < 2; ++i) {
        const float o1 = 100.f * (v[i] - ymin) / rng;            // in [0,100]
        const float s  = 100.f / (1.f + expf(-(TEMPERATURE * (o1 * 0.01f - THRESHOLD * 0.01f))));
        v[i] = 100.f * (s - smin) / srng;
    }
    *reinterpret_cast<f32x2*>(&y[base]) = v;
}

extern "C" void kernel_launch(void* const* d_in, const int* in_sizes, int n_in,
                              void* d_out, int out_size, void* d_ws, size_t ws_size,
                              hipStream_t stream) {
    const float* x      = (const float*)d_in[0];
    const int*   freq   = (const int*)d_in[1];
    const int*   orient = (const int*)d_in[2];
    const float* fb     = (const float*)d_in[3];
    float*       out    = (float*)d_out;       // doubles as y scratch
    float2*      partial = (float2*)d_ws;      // 4096 per-block {min,max}

    // 512 tiles x 8 slices; consecutive gid = same tile across the 8 XCDs
    filter_sliced<<<dim3(NBLK), 128, 0, stream>>>(x, freq, orient, fb, out, partial);

    // 512 blocks x 256 threads x 2 px; each block inlines the partial-reduce
    filter_final<<<(HTOT * WTOT) / 512, 256, 0, stream>>>(out, partial);
}

// Round 13
// 42.712 us; speedup vs baseline: 2.7314x; 2.7314x over previous
//
#include <hip/hip_runtime.h>
#include <math.h>

#define FDIM  100
#define ODIM  180
#define HTOT  512
#define WTOT  512
#define TILE  32               // 32x32 pixel tile per (tile,slice) block
#define REG   48               // staged region = TILE + 16
#define LDSW  49
#define NSLICE 8
#define SLICE_SZ 2250          // 18000/8 -> per-XCD-resident 2.6 MB slice
#define NTILE 256              // (512/32)^2
#define NBLK  (NTILE * NSLICE) // 2048 blocks  -- VERIFIED geometry for gid%8->XCD
#define TEMPERATURE 20.0f
#define THRESHOLD   55.0f

typedef float f32x4 __attribute__((ext_vector_type(4)));

// NOTE (R12 lesson): the slice->XCD locality ONLY held at 256-thread blocks with
// a 2048-block grid (FETCH 24 MB). 128-thread/4096-block geometry broke the
// gid%8->XCD mapping (FETCH 278 MB, 3.4x slower). Do not change this geometry.

// ws layout (bytes): [0, 16384) : float2 partial[2048] — all written every call
__global__ __launch_bounds__(256) void filter_sliced(
    const float* __restrict__ x,
    const int*   __restrict__ freq,
    const int*   __restrict__ orient,
    const float* __restrict__ fb,
    float*       __restrict__ y,
    float2*      __restrict__ partial)
{
    __shared__ float tile[REG][LDSW];          // 48 x 49 floats = 9408 B
    __shared__ int   sel[TILE * TILE];         // packed (idx<<10)|p, 4096 B
    __shared__ unsigned int nsel;

    const int gid   = blockIdx.x;
    const int slice = gid & (NSLICE - 1);
    const int t     = gid >> 3;                // tile id 0..255
    const int bx    = t & 15, by = t >> 4;
    const int tid   = threadIdx.x;
    const int lane  = tid & 63;

    if (tid == 0) nsel = 0;
    __syncthreads();

    // pass 1: per-pixel filter index + wave-aggregated compaction (1 atomic/wave/pass)
    const int lo = slice * SLICE_SZ;
    #pragma unroll
    for (int k = 0; k < 4; ++k) {
        const int p  = tid + k * 256;
        const int pr = p >> 5, pc = p & 31;
        const int pid = (by * TILE + pr) * WTOT + bx * TILE + pc;
        int f0 = freq[pid] - 1;
        int o0 = orient[pid] - 1;
        f0 = f0 < 0 ? 0 : (f0 > FDIM - 1 ? FDIM - 1 : f0);
        o0 = o0 < 0 ? 0 : (o0 > ODIM - 1 ? ODIM - 1 : o0);
        const int idx = f0 * ODIM + o0;
        const bool want = (idx >= lo && idx < lo + SLICE_SZ);
        const unsigned long long mask = __ballot(want);
        unsigned int base = 0;
        if (lane == 0) base = atomicAdd(&nsel, (unsigned int)__popcll(mask));
        base = __shfl(base, 0, 64);
        if (want) {
            const int pos = __popcll(mask & ((1ULL << lane) - 1ULL));
            sel[base + pos] = (idx << 10) | p;
        }
    }

    // stage 48x48 input region (zero-padded at image borders)
    const int h0 = by * TILE - 8;
    const int w0 = bx * TILE - 8;
    for (int i = tid; i < REG * REG; i += 256) {
        const int r = i / REG, c = i - r * REG;
        const int gh = h0 + r, gw = w0 + c;
        float v = 0.f;
        if (gh >= 0 && gh < HTOT && gw >= 0 && gw < WTOT)
            v = x[gh * WTOT + gw];
        tile[r][c] = v;
    }
    __syncthreads();

    const unsigned int m = nsel;
    const int l  = tid & 15;                   // lane within quarter-wave
    const int qw = tid >> 4;                   // quarter-wave id 0..15

    // odd-j rotation: odd qws traverse the j-schedule 9 positions later ->
    // their LDS bank windows sit ~16 banks from even qws' (bank shift =
    // (9*16*... ) mod 32 = 16, odd rotation). Bijective reorder, sum unchanged.
    const int rot = (qw & 1) * 9;

    int offs[18];
    #pragma unroll
    for (int j = 0; j < 18; ++j) {
        int jr = j + rot; if (jr >= 18) jr -= 18;
        const int e = jr * 16 + l;
        offs[j] = (e / 17) * LDSW + (e % 17);
    }

    float mn = 3.4e38f, mx = -3.4e38f;

    // each quarter-wave takes every 16th selected pixel (avg ~8 each);
    // batch the 19 filter loads, let the compiler schedule (explicit
    // rotate-pipeline variant regressed to 43 us — R10 post-mortem)
    for (unsigned int s = qw; s < m; s += 16) {
        const int packed = sel[s];
        const int tp  = packed & 1023;
        const int ppy = tp >> 5, ppx = tp & 31;
        const float* __restrict__ kf = fb + (size_t)(packed >> 10) * 289;

        float kv[18];
        #pragma unroll
        for (int j = 0; j < 18; ++j) {
            int jr = j + rot; if (jr >= 18) jr -= 18;
            kv[j] = kf[jr * 16 + l];
        }
        const float kt = kf[288];

        const float* __restrict__ base = &tile[ppy][ppx];
        float a0 = 0.f, a1 = 0.f, a2 = 0.f, a3 = 0.f;
        #pragma unroll
        for (int j = 0; j < 16; j += 4) {
            a0 = fmaf(kv[j    ], base[offs[j    ]], a0);
            a1 = fmaf(kv[j + 1], base[offs[j + 1]], a1);
            a2 = fmaf(kv[j + 2], base[offs[j + 2]], a2);
            a3 = fmaf(kv[j + 3], base[offs[j + 3]], a3);
        }
        a0 = fmaf(kv[16], base[offs[16]], a0);
        a1 = fmaf(kv[17], base[offs[17]], a1);
        float acc = (a0 + a1) + (a2 + a3);
        if (l == 0) acc = fmaf(kt, base[16 * LDSW + 16], acc);  // e = 288 tail

        // butterfly sum over the 16-lane group
        #pragma unroll
        for (int off = 8; off; off >>= 1)
            acc += __shfl_xor(acc, off, 64);

        if (l == 0)
            y[(by * TILE + ppy) * WTOT + bx * TILE + ppx] = acc;
        mn = fminf(mn, acc);
        mx = fmaxf(mx, acc);
    }

    // ---- block min/max reduce, then ONE plain store to a unique slot ----
    #pragma unroll
    for (int off = 32; off > 0; off >>= 1) {
        mn = fminf(mn, __shfl_down(mn, off, 64));
        mx = fmaxf(mx, __shfl_down(mx, off, 64));
    }
    __shared__ float smn[4], smx[4];
    const int wid = tid >> 6;
    if (lane == 0) { smn[wid] = mn; smx[wid] = mx; }
    __syncthreads();
    if (tid == 0) {
        float bmn = smn[0], bmx = smx[0];
        #pragma unroll
        for (int i = 1; i < 4; ++i) {
            bmn = fminf(bmn, smn[i]);
            bmx = fmaxf(bmx, smx[i]);
        }
        partial[gid] = make_float2(bmn, bmx);
    }
}

// fused: re-reduce the 2048 partials (16 KB, L2-hit) + transform 4 px/thread
__global__ __launch_bounds__(256) void filter_final(
    float* __restrict__ y,
    const float2* __restrict__ partial)
{
    const int tid = threadIdx.x;
    float mn = 3.4e38f, mx = -3.4e38f;
    for (int i = tid; i < NBLK; i += 256) {
        const float2 p = partial[i];
        mn = fminf(mn, p.x);
        mx = fmaxf(mx, p.y);
    }
    #pragma unroll
    for (int off = 32; off > 0; off >>= 1) {
        mn = fminf(mn, __shfl_down(mn, off, 64));
        mx = fmaxf(mx, __shfl_down(mx, off, 64));
    }
    __shared__ float smn[4], smx[4];
    const int wid = tid >> 6, lane = tid & 63;
    if (lane == 0) { smn[wid] = mn; smx[wid] = mx; }
    __syncthreads();
    __shared__ float sfin[2];
    if (tid == 0) {
        float bmn = smn[0], bmx = smx[0];
        #pragma unroll
        for (int i = 1; i < 4; ++i) {
            bmn = fminf(bmn, smn[i]);
            bmx = fmaxf(bmx, smx[i]);
        }
        sfin[0] = bmn; sfin[1] = bmx;
    }
    __syncthreads();

    const float ymin = sfin[0];
    const float rng  = fmaxf(sfin[1] - ymin, 1e-8f);
    const float smin = 100.f / (1.f + expf( 11.f));   // 100*sigmoid(-11)
    const float smax = 100.f / (1.f + expf(-9.f));    // 100*sigmoid(+9)
    const float srng = fmaxf(smax - smin, 1e-8f);

    const int base = blockIdx.x * 1024 + tid * 4;
    f32x4 v = *reinterpret_cast<const f32x4*>(&y[base]);
    #pragma unroll
    for (int i = 0; i < 4; ++i) {
        const float o1 = 100.f * (v[i] - ymin) / rng;            // in [0,100]
        const float s  = 100.f / (1.f + expf(-(TEMPERATURE * (o1 * 0.01f - THRESHOLD * 0.01f))));
        v[i] = 100.f * (s - smin) / srng;
    }
    *reinterpret_cast<f32x4*>(&y[base]) = v;
}

extern "C" void kernel_launch(void* const* d_in, const int* in_sizes, int n_in,
                              void* d_out, int out_size, void* d_ws, size_t ws_size,
                              hipStream_t stream) {
    const float* x      = (const float*)d_in[0];
    const int*   freq   = (const int*)d_in[1];
    const int*   orient = (const int*)d_in[2];
    const float* fb     = (const float*)d_in[3];
    float*       out    = (float*)d_out;       // doubles as y scratch
    float2*      partial = (float2*)d_ws;      // 2048 per-block {min,max}

    // 256 tiles x 8 slices; consecutive gid = same tile across the 8 XCDs
    filter_sliced<<<dim3(NBLK), 256, 0, stream>>>(x, freq, orient, fb, out, partial);

    // 256 blocks x 256 threads x 4 px; each block inlines the partial-reduce
    filter_final<<<(HTOT * WTOT) / 1024, 256, 0, stream>>>(out, partial);
}

// Round 15
// 34.030 us; speedup vs baseline: 3.4282x; 1.2551x over previous
//
#include <hip/hip_runtime.h>
#include <math.h>

#define FDIM  100
#define ODIM  180
#define HTOT  512
#define WTOT  512
#define TILE  32               // 32x32 pixel tile per (tile,slice) block
#define REG   48               // staged region = TILE + 16
#define LDSW  49
#define NSLICE 8
#define SLICE_SZ 2250          // 18000/8 -> per-XCD-resident 2.6 MB slice
#define NTILE 256              // (512/32)^2
#define NBLK  (NTILE * NSLICE) // 2048 blocks  -- VERIFIED geometry for gid%8->XCD
#define TEMPERATURE 20.0f
#define THRESHOLD   55.0f

typedef float f32x4 __attribute__((ext_vector_type(4)));

// LESSONS (do not regress):
//  R12: slice->XCD locality ONLY verified at 256-thread / 2048-block geometry.
//  R13: odd-j rotation raised conflicts AND VALU cost.
//  R14: hipLaunchCooperativeKernel silently fails under graph capture here.
//  R10: explicit register rotate-pipelining regressed (compiler schedules better).
//  R9:  filter repack (alignment fix) cost more than it saved — L2 volume, not
//       line splits, is the filter-path cost.

// ws layout (bytes): [0, 16384) : float2 partial[2048] — all written every call
__global__ __launch_bounds__(256) void filter_sliced(
    const float* __restrict__ x,
    const int*   __restrict__ freq,
    const int*   __restrict__ orient,
    const float* __restrict__ fb,
    float*       __restrict__ y,
    float2*      __restrict__ partial)
{
    __shared__ float tile[REG][LDSW];          // 48 x 49 floats = 9408 B
    __shared__ int   sel[TILE * TILE];         // packed (idx<<10)|p, 4096 B
    __shared__ unsigned int nsel;

    const int gid   = blockIdx.x;
    const int slice = gid & (NSLICE - 1);
    const int t     = gid >> 3;                // tile id 0..255
    const int bx    = t & 15, by = t >> 4;
    const int tid   = threadIdx.x;
    const int lane  = tid & 63;

    if (tid == 0) nsel = 0;
    __syncthreads();

    // pass 1: per-pixel filter index + wave-aggregated compaction (1 atomic/wave/pass)
    const int lo = slice * SLICE_SZ;
    #pragma unroll
    for (int k = 0; k < 4; ++k) {
        const int p  = tid + k * 256;
        const int pr = p >> 5, pc = p & 31;
        const int pid = (by * TILE + pr) * WTOT + bx * TILE + pc;
        int f0 = freq[pid] - 1;
        int o0 = orient[pid] - 1;
        f0 = f0 < 0 ? 0 : (f0 > FDIM - 1 ? FDIM - 1 : f0);
        o0 = o0 < 0 ? 0 : (o0 > ODIM - 1 ? ODIM - 1 : o0);
        const int idx = f0 * ODIM + o0;
        const bool want = (idx >= lo && idx < lo + SLICE_SZ);
        const unsigned long long mask = __ballot(want);
        unsigned int base = 0;
        if (lane == 0) base = atomicAdd(&nsel, (unsigned int)__popcll(mask));
        base = __shfl(base, 0, 64);
        if (want) {
            const int pos = __popcll(mask & ((1ULL << lane) - 1ULL));
            sel[base + pos] = (idx << 10) | p;
        }
    }

    // stage 48x48 input region (zero-padded at image borders)
    const int h0 = by * TILE - 8;
    const int w0 = bx * TILE - 8;
    for (int i = tid; i < REG * REG; i += 256) {
        const int r = i / REG, c = i - r * REG;
        const int gh = h0 + r, gw = w0 + c;
        float v = 0.f;
        if (gh >= 0 && gh < HTOT && gw >= 0 && gw < WTOT)
            v = x[gh * WTOT + gw];
        tile[r][c] = v;
    }
    __syncthreads();

    const unsigned int m = nsel;
    const int l  = tid & 15;                   // lane within quarter-wave
    const int qw = tid >> 4;                   // quarter-wave id 0..15

    int offs[18];
    #pragma unroll
    for (int j = 0; j < 18; ++j) {
        const int e = j * 16 + l;
        offs[j] = (e / 17) * LDSW + (e % 17);
    }

    float mn = 3.4e38f, mx = -3.4e38f;

    // each quarter-wave takes every 16th selected pixel (avg ~8 each);
    // batch the 19 filter loads, let the compiler schedule
    for (unsigned int s = qw; s < m; s += 16) {
        const int packed = sel[s];
        const int tp  = packed & 1023;
        const int ppy = tp >> 5, ppx = tp & 31;
        const float* __restrict__ kf = fb + (size_t)(packed >> 10) * 289;

        float kv[18];
        #pragma unroll
        for (int j = 0; j < 18; ++j) kv[j] = kf[j * 16 + l];
        const float kt = kf[288];

        const float* __restrict__ base = &tile[ppy][ppx];
        float a0 = 0.f, a1 = 0.f, a2 = 0.f, a3 = 0.f;
        #pragma unroll
        for (int j = 0; j < 16; j += 4) {
            a0 = fmaf(kv[j    ], base[offs[j    ]], a0);
            a1 = fmaf(kv[j + 1], base[offs[j + 1]], a1);
            a2 = fmaf(kv[j + 2], base[offs[j + 2]], a2);
            a3 = fmaf(kv[j + 3], base[offs[j + 3]], a3);
        }
        a0 = fmaf(kv[16], base[offs[16]], a0);
        a1 = fmaf(kv[17], base[offs[17]], a1);
        float acc = (a0 + a1) + (a2 + a3);
        if (l == 0) acc = fmaf(kt, base[16 * LDSW + 16], acc);  // e = 288 tail

        // butterfly sum over the 16-lane group
        #pragma unroll
        for (int off = 8; off; off >>= 1)
            acc += __shfl_xor(acc, off, 64);

        if (l == 0)
            y[(by * TILE + ppy) * WTOT + bx * TILE + ppx] = acc;
        mn = fminf(mn, acc);
        mx = fmaxf(mx, acc);
    }

    // ---- block min/max reduce, then ONE plain store to a unique slot ----
    #pragma unroll
    for (int off = 32; off > 0; off >>= 1) {
        mn = fminf(mn, __shfl_down(mn, off, 64));
        mx = fmaxf(mx, __shfl_down(mx, off, 64));
    }
    __shared__ float smn[4], smx[4];
    const int wid = tid >> 6;
    if (lane == 0) { smn[wid] = mn; smx[wid] = mx; }
    __syncthreads();
    if (tid == 0) {
        float bmn = smn[0], bmx = smx[0];
        #pragma unroll
        for (int i = 1; i < 4; ++i) {
            bmn = fminf(bmn, smn[i]);
            bmx = fmaxf(bmx, smx[i]);
        }
        partial[gid] = make_float2(bmn, bmx);
    }
}

// fused: re-reduce the 2048 partials (16 KB, L2-hit) + transform 4 px/thread
__global__ __launch_bounds__(256) void filter_final(
    float* __restrict__ y,
    const float2* __restrict__ partial)
{
    const int tid = threadIdx.x;
    float mn = 3.4e38f, mx = -3.4e38f;
    for (int i = tid; i < NBLK; i += 256) {
        const float2 p = partial[i];
        mn = fminf(mn, p.x);
        mx = fmaxf(mx, p.y);
    }
    #pragma unroll
    for (int off = 32; off > 0; off >>= 1) {
        mn = fminf(mn, __shfl_down(mn, off, 64));
        mx = fmaxf(mx, __shfl_down(mx, off, 64));
    }
    __shared__ float smn[4], smx[4];
    const int wid = tid >> 6, lane = tid & 63;
    if (lane == 0) { smn[wid] = mn; smx[wid] = mx; }
    __syncthreads();
    __shared__ float sfin[2];
    if (tid == 0) {
        float bmn = smn[0], bmx = smx[0];
        #pragma unroll
        for (int i = 1; i < 4; ++i) {
            bmn = fminf(bmn, smn[i]);
            bmx = fmaxf(bmx, smx[i]);
        }
        sfin[0] = bmn; sfin[1] = bmx;
    }
    __syncthreads();

    const float ymin = sfin[0];
    const float rng  = fmaxf(sfin[1] - ymin, 1e-8f);
    const float smin = 100.f / (1.f + expf( 11.f));   // 100*sigmoid(-11)
    const float smax = 100.f / (1.f + expf(-9.f));    // 100*sigmoid(+9)
    const float srng = fmaxf(smax - smin, 1e-8f);

    const int base = blockIdx.x * 1024 + tid * 4;
    f32x4 v = *reinterpret_cast<const f32x4*>(&y[base]);
    #pragma unroll
    for (int i = 0; i < 4; ++i) {
        const float o1 = 100.f * (v[i] - ymin) / rng;            // in [0,100]
        const float s  = 100.f / (1.f + expf(-(TEMPERATURE * (o1 * 0.01f - THRESHOLD * 0.01f))));
        v[i] = 100.f * (s - smin) / srng;
    }
    *reinterpret_cast<f32x4*>(&y[base]) = v;
}

extern "C" void kernel_launch(void* const* d_in, const int* in_sizes, int n_in,
                              void* d_out, int out_size, void* d_ws, size_t ws_size,
                              hipStream_t stream) {
    const float* x      = (const float*)d_in[0];
    const int*   freq   = (const int*)d_in[1];
    const int*   orient = (const int*)d_in[2];
    const float* fb     = (const float*)d_in[3];
    float*       out    = (float*)d_out;       // doubles as y scratch
    float2*      partial = (float2*)d_ws;      // 2048 per-block {min,max}

    // 256 tiles x 8 slices; consecutive gid = same tile across the 8 XCDs
    filter_sliced<<<dim3(NBLK), 256, 0, stream>>>(x, freq, orient, fb, out, partial);

    // 256 blocks x 256 threads x 4 px; each block inlines the partial-reduce
    filter_final<<<(HTOT * WTOT) / 1024, 256, 0, stream>>>(out, partial);
}

// Round 16
// 32.854 us; speedup vs baseline: 3.5509x; 1.0358x over previous
//
#include <hip/hip_runtime.h>
#include <math.h>

#define FDIM  100
#define ODIM  180
#define HTOT  512
#define WTOT  512
#define TILE  32               // 32x32 pixel tile per (tile,slice) block
#define REG   48               // staged region = TILE + 16
#define LDSW  49
#define NSLICE 8
#define SLICE_SZ 2250          // 18000/8 -> per-XCD-resident 2.6 MB slice
#define NTILE 256              // (512/32)^2
#define NBLK  (NTILE * NSLICE) // 2048 blocks  -- VERIFIED geometry for gid%8->XCD
#define TEMPERATURE 20.0f
#define THRESHOLD   55.0f

typedef float f32x4 __attribute__((ext_vector_type(4)));

// LESSONS (do not regress):
//  R12: slice->XCD locality ONLY verified at 256-thread / 2048-block geometry.
//  R13: odd-j rotation raised conflicts AND VALU cost.
//  R14: hipLaunchCooperativeKernel silently fails under graph capture here.
//  R10: explicit register rotate-pipelining regressed (compiler schedules better).
//  R9:  filter repack (alignment) null — L2 volume, not line splits, is the cost.
//  R15 theory: LDS pipe is critical (~25 DS instr/trip incl. shfl bpermutes) ->
//       move the 16-lane butterfly to VALU DPP row-rotates.

// DPP row_ror:N within the 16-lane row (CDNA row = 16 lanes).
// acc += ror8; += ror4; += ror2; += ror1  => all 16 lanes hold the row total.
template <int CTRL>
__device__ __forceinline__ float dpp_ror_add(float v) {
    const int r = __builtin_amdgcn_mov_dpp(__float_as_int(v), CTRL, 0xf, 0xf, false);
    return v + __int_as_float(r);
}

// ws layout (bytes): [0, 16384) : float2 partial[2048] — all written every call
__global__ __launch_bounds__(256) void filter_sliced(
    const float* __restrict__ x,
    const int*   __restrict__ freq,
    const int*   __restrict__ orient,
    const float* __restrict__ fb,
    float*       __restrict__ y,
    float2*      __restrict__ partial)
{
    __shared__ float tile[REG][LDSW];          // 48 x 49 floats = 9408 B
    __shared__ int   sel[TILE * TILE];         // packed (idx<<10)|p, 4096 B
    __shared__ unsigned int nsel;

    const int gid   = blockIdx.x;
    const int slice = gid & (NSLICE - 1);
    const int t     = gid >> 3;                // tile id 0..255
    const int bx    = t & 15, by = t >> 4;
    const int tid   = threadIdx.x;
    const int lane  = tid & 63;

    if (tid == 0) nsel = 0;
    __syncthreads();

    // pass 1: per-pixel filter index + wave-aggregated compaction (1 atomic/wave/pass)
    const int lo = slice * SLICE_SZ;
    #pragma unroll
    for (int k = 0; k < 4; ++k) {
        const int p  = tid + k * 256;
        const int pr = p >> 5, pc = p & 31;
        const int pid = (by * TILE + pr) * WTOT + bx * TILE + pc;
        int f0 = freq[pid] - 1;
        int o0 = orient[pid] - 1;
        f0 = f0 < 0 ? 0 : (f0 > FDIM - 1 ? FDIM - 1 : f0);
        o0 = o0 < 0 ? 0 : (o0 > ODIM - 1 ? ODIM - 1 : o0);
        const int idx = f0 * ODIM + o0;
        const bool want = (idx >= lo && idx < lo + SLICE_SZ);
        const unsigned long long mask = __ballot(want);
        unsigned int base = 0;
        if (lane == 0) base = atomicAdd(&nsel, (unsigned int)__popcll(mask));
        base = __shfl(base, 0, 64);
        if (want) {
            const int pos = __popcll(mask & ((1ULL << lane) - 1ULL));
            sel[base + pos] = (idx << 10) | p;
        }
    }

    // stage 48x48 input region (zero-padded at image borders)
    const int h0 = by * TILE - 8;
    const int w0 = bx * TILE - 8;
    for (int i = tid; i < REG * REG; i += 256) {
        const int r = i / REG, c = i - r * REG;
        const int gh = h0 + r, gw = w0 + c;
        float v = 0.f;
        if (gh >= 0 && gh < HTOT && gw >= 0 && gw < WTOT)
            v = x[gh * WTOT + gw];
        tile[r][c] = v;
    }
    __syncthreads();

    const unsigned int m = nsel;
    const int l  = tid & 15;                   // lane within quarter-wave
    const int qw = tid >> 4;                   // quarter-wave id 0..15

    int offs[18];
    #pragma unroll
    for (int j = 0; j < 18; ++j) {
        const int e = j * 16 + l;
        offs[j] = (e / 17) * LDSW + (e % 17);
    }

    float mn = 3.4e38f, mx = -3.4e38f;

    // each quarter-wave takes every 16th selected pixel (avg ~8 each);
    // batch the 19 filter loads, let the compiler schedule
    for (unsigned int s = qw; s < m; s += 16) {
        const int packed = sel[s];
        const int tp  = packed & 1023;
        const int ppy = tp >> 5, ppx = tp & 31;
        const float* __restrict__ kf = fb + (size_t)(packed >> 10) * 289;

        float kv[18];
        #pragma unroll
        for (int j = 0; j < 18; ++j) kv[j] = kf[j * 16 + l];
        const float kt = kf[288];

        const float* __restrict__ base = &tile[ppy][ppx];
        float a0 = 0.f, a1 = 0.f, a2 = 0.f, a3 = 0.f;
        #pragma unroll
        for (int j = 0; j < 16; j += 4) {
            a0 = fmaf(kv[j    ], base[offs[j    ]], a0);
            a1 = fmaf(kv[j + 1], base[offs[j + 1]], a1);
            a2 = fmaf(kv[j + 2], base[offs[j + 2]], a2);
            a3 = fmaf(kv[j + 3], base[offs[j + 3]], a3);
        }
        a0 = fmaf(kv[16], base[offs[16]], a0);
        a1 = fmaf(kv[17], base[offs[17]], a1);
        float acc = (a0 + a1) + (a2 + a3);
        if (l == 0) acc = fmaf(kt, base[16 * LDSW + 16], acc);  // e = 288 tail

        // 16-lane total via VALU DPP row-rotates (no LDS-pipe traffic)
        acc = dpp_ror_add<0x128>(acc);   // row_ror:8
        acc = dpp_ror_add<0x124>(acc);   // row_ror:4
        acc = dpp_ror_add<0x122>(acc);   // row_ror:2
        acc = dpp_ror_add<0x121>(acc);   // row_ror:1

        if (l == 0)
            y[(by * TILE + ppy) * WTOT + bx * TILE + ppx] = acc;
        mn = fminf(mn, acc);
        mx = fmaxf(mx, acc);
    }

    // ---- block min/max reduce, then ONE plain store to a unique slot ----
    #pragma unroll
    for (int off = 32; off > 0; off >>= 1) {
        mn = fminf(mn, __shfl_down(mn, off, 64));
        mx = fmaxf(mx, __shfl_down(mx, off, 64));
    }
    __shared__ float smn[4], smx[4];
    const int wid = tid >> 6;
    if (lane == 0) { smn[wid] = mn; smx[wid] = mx; }
    __syncthreads();
    if (tid == 0) {
        float bmn = smn[0], bmx = smx[0];
        #pragma unroll
        for (int i = 1; i < 4; ++i) {
            bmn = fminf(bmn, smn[i]);
            bmx = fmaxf(bmx, smx[i]);
        }
        partial[gid] = make_float2(bmn, bmx);
    }
}

// fused: re-reduce the 2048 partials (16 KB, L2-hit) + transform 4 px/thread
__global__ __launch_bounds__(256) void filter_final(
    float* __restrict__ y,
    const float2* __restrict__ partial)
{
    const int tid = threadIdx.x;
    float mn = 3.4e38f, mx = -3.4e38f;
    for (int i = tid; i < NBLK; i += 256) {
        const float2 p = partial[i];
        mn = fminf(mn, p.x);
        mx = fmaxf(mx, p.y);
    }
    #pragma unroll
    for (int off = 32; off > 0; off >>= 1) {
        mn = fminf(mn, __shfl_down(mn, off, 64));
        mx = fmaxf(mx, __shfl_down(mx, off, 64));
    }
    __shared__ float smn[4], smx[4];
    const int wid = tid >> 6, lane = tid & 63;
    if (lane == 0) { smn[wid] = mn; smx[wid] = mx; }
    __syncthreads();
    __shared__ float sfin[2];
    if (tid == 0) {
        float bmn = smn[0], bmx = smx[0];
        #pragma unroll
        for (int i = 1; i < 4; ++i) {
            bmn = fminf(bmn, smn[i]);
            bmx = fmaxf(bmx, smx[i]);
        }
        sfin[0] = bmn; sfin[1] = bmx;
    }
    __syncthreads();

    const float ymin = sfin[0];
    const float rng  = fmaxf(sfin[1] - ymin, 1e-8f);
    const float smin = 100.f / (1.f + expf( 11.f));   // 100*sigmoid(-11)
    const float smax = 100.f / (1.f + expf(-9.f));    // 100*sigmoid(+9)
    const float srng = fmaxf(smax - smin, 1e-8f);

    const int base = blockIdx.x * 1024 + tid * 4;
    f32x4 v = *reinterpret_cast<const f32x4*>(&y[base]);
    #pragma unroll
    for (int i = 0; i < 4; ++i) {
        const float o1 = 100.f * (v[i] - ymin) / rng;            // in [0,100]
        const float s  = 100.f / (1.f + expf(-(TEMPERATURE * (o1 * 0.01f - THRESHOLD * 0.01f))));
        v[i] = 100.f * (s - smin) / srng;
    }
    *reinterpret_cast<f32x4*>(&y[base]) = v;
}

extern "C" void kernel_launch(void* const* d_in, const int* in_sizes, int n_in,
                              void* d_out, int out_size, void* d_ws, size_t ws_size,
                              hipStream_t stream) {
    const float* x      = (const float*)d_in[0];
    const int*   freq   = (const int*)d_in[1];
    const int*   orient = (const int*)d_in[2];
    const float* fb     = (const float*)d_in[3];
    float*       out    = (float*)d_out;       // doubles as y scratch
    float2*      partial = (float2*)d_ws;      // 2048 per-block {min,max}

    // 256 tiles x 8 slices; consecutive gid = same tile across the 8 XCDs
    filter_sliced<<<dim3(NBLK), 256, 0, stream>>>(x, freq, orient, fb, out, partial);

    // 256 blocks x 256 threads x 4 px; each block inlines the partial-reduce
    filter_final<<<(HTOT * WTOT) / 1024, 256, 0, stream>>>(out, partial);
}